// Round 3
// baseline (2259.969 us; speedup 1.0000x reference)
//
#include <hip/hip_runtime.h>
#include <hip/hip_bf16.h>

#define BB   4096
#define DIN  4096
#define DE   1024
#define NE   6
#define EPS  1e-5f

typedef __attribute__((ext_vector_type(8))) short s16x8;
typedef __attribute__((ext_vector_type(4))) float f32x4;

// ---------------------------------------------------------------------------
// bf16 helpers (round-to-nearest-even)
__device__ __forceinline__ unsigned short f2bf(float f) {
    unsigned int u = __builtin_bit_cast(unsigned int, f);
    u = (u + 0x7fffu + ((u >> 16) & 1u)) >> 16;
    return (unsigned short)u;
}
__device__ __forceinline__ float bf2f(unsigned short h) {
    unsigned int u = (unsigned int)h << 16;
    return __builtin_bit_cast(float, u);
}

__device__ __forceinline__ void gload16(const void* g, void* l) {
    __builtin_amdgcn_global_load_lds(
        (const __attribute__((address_space(1))) void*)g,
        (__attribute__((address_space(3))) void*)l, 16, 0, 0);
}

// ---------------------------------------------------------------------------
__global__ void zero_k(float* __restrict__ p, int n) {
    int i = blockIdx.x * 256 + threadIdx.x;
    if (i < n) p[i] = 0.f;
}

// ---------------------------------------------------------------------------
// elementwise split: f32 -> (hi bf16, lo bf16), vectorized x4
__global__ void split_k(const float* __restrict__ in, unsigned short* __restrict__ h,
                        unsigned short* __restrict__ l, long n4)
{
    long stride = (long)gridDim.x * 256;
    for (long i = blockIdx.x * 256L + threadIdx.x; i < n4; i += stride) {
        float4 v = ((const float4*)in)[i];
        const float* vp = (const float*)&v;
        ushort4 hh, ll;
        unsigned short* hp = (unsigned short*)&hh;
        unsigned short* lp = (unsigned short*)&ll;
        #pragma unroll
        for (int j = 0; j < 4; ++j) {
            unsigned short hb = f2bf(vp[j]);
            hp[j] = hb;
            lp[j] = f2bf(vp[j] - bf2f(hb));
        }
        ((ushort4*)h)[i] = hh;
        ((ushort4*)l)[i] = ll;
    }
}

// ---------------------------------------------------------------------------
// transpose + split: W [K][N] f32 -> Th/Tl [N][K] bf16  (per-expert via grid.z)
__global__ void tsplit_k(const float* __restrict__ W, unsigned short* __restrict__ Th,
                         unsigned short* __restrict__ Tl, int K, int N, long sW, long sT)
{
    __shared__ float t[32][33];
    const int n0 = blockIdx.x * 32, k0 = blockIdx.y * 32;
    W  += (long)blockIdx.z * sW;
    Th += (long)blockIdx.z * sT;
    Tl += (long)blockIdx.z * sT;
    const int tx = threadIdx.x & 31, ty = threadIdx.x >> 5;
    #pragma unroll
    for (int r = 0; r < 4; ++r) {
        int k = ty + r * 8;
        t[k][tx] = W[(long)(k0 + k) * N + n0 + tx];
    }
    __syncthreads();
    #pragma unroll
    for (int r = 0; r < 4; ++r) {
        int nn = ty + r * 8;
        float v = t[tx][nn];
        long o = (long)(n0 + nn) * K + k0 + tx;
        unsigned short hb = f2bf(v);
        Th[o] = hb;
        Tl[o] = f2bf(v - bf2f(hb));
    }
}

// ---------------------------------------------------------------------------
// Gating stage 1 (fp32, K-split x4, atomic accumulate into pre-zeroed t1)
__global__ __launch_bounds__(256) void gate1_kernel(
    const float* __restrict__ x, const float* __restrict__ Wg1, float* __restrict__ t1)
{
    __shared__ float Xs[64][65];
    __shared__ float Ws[64][64];
    const int tid  = threadIdx.x;
    const int row0 = blockIdx.x * 64;
    const int kb   = blockIdx.y * 1024;
    const int r0 = (tid >> 4) * 4, c0 = (tid & 15) * 4;
    float acc[4][4] = {};
    for (int k0 = kb; k0 < kb + 1024; k0 += 64) {
        #pragma unroll
        for (int i = 0; i < 16; ++i) {
            int idx = tid + i * 256;
            int r = idx >> 6, c = idx & 63;
            Xs[c][r] = x[(long)(row0 + r) * DIN + k0 + c];
            Ws[r][c] = Wg1[(long)(k0 + r) * 64 + c];
        }
        __syncthreads();
        #pragma unroll 16
        for (int kk = 0; kk < 64; ++kk) {
            float a[4], b[4];
            #pragma unroll
            for (int i = 0; i < 4; ++i) a[i] = Xs[kk][r0 + i];
            #pragma unroll
            for (int j = 0; j < 4; ++j) b[j] = Ws[kk][c0 + j];
            #pragma unroll
            for (int i = 0; i < 4; ++i)
                #pragma unroll
                for (int j = 0; j < 4; ++j) acc[i][j] += a[i] * b[j];
        }
        __syncthreads();
    }
    #pragma unroll
    for (int i = 0; i < 4; ++i)
        #pragma unroll
        for (int j = 0; j < 4; ++j)
            atomicAdd(&t1[(long)(row0 + r0 + i) * 64 + c0 + j], acc[i][j]);
}

// Gating stage 2: gate = softmax(relu(t1 + bg1) @ Wg2 + bg2)
__global__ void gate2_kernel(const float* __restrict__ t1, const float* __restrict__ Wg2,
                             const float* __restrict__ bg1, const float* __restrict__ bg2,
                             float* __restrict__ gate)
{
    __shared__ float W[64 * NE];
    __shared__ float b1[64];
    __shared__ float bsh[NE];
    const int tid = threadIdx.x;
    for (int i = tid; i < 64 * NE; i += 256) W[i] = Wg2[i];
    if (tid < 64) b1[tid] = bg1[tid];
    if (tid < NE) bsh[tid] = bg2[tid];
    __syncthreads();
    int b = blockIdx.x * 256 + tid;
    const float* tr = t1 + (long)b * 64;
    float l[NE];
    #pragma unroll
    for (int e = 0; e < NE; ++e) l[e] = bsh[e];
    for (int k = 0; k < 64; ++k) {
        float tv = fmaxf(tr[k] + b1[k], 0.f);
        #pragma unroll
        for (int e = 0; e < NE; ++e) l[e] += tv * W[k * NE + e];
    }
    float m = l[0];
    #pragma unroll
    for (int e = 1; e < NE; ++e) m = fmaxf(m, l[e]);
    float s = 0.f;
    #pragma unroll
    for (int e = 0; e < NE; ++e) { l[e] = expf(l[e] - m); s += l[e]; }
    float inv = 1.f / s;
    #pragma unroll
    for (int e = 0; e < NE; ++e) gate[(long)b * NE + e] = l[e] * inv;
}

// ---------------------------------------------------------------------------
// Split-bf16 MFMA GEMM: C[M,N] ~= A[M,K] @ B[K,N] in fp32 precision via
// AhBh + AlBh + AhBl.  A given as (Ah,Al) [M][K] bf16; B as transposed
// (Bh,Bl) [N][K] bf16 (+ grid.z * strideB).  128x128 tile, BK=64, 4 waves.
// LDS XOR-swizzle (chunk ^= row&7) applied via inverse-swizzled GLOBAL source
// (linear LDS dest — rule #21) and swizzled ds_read address.
__device__ __forceinline__ void stage4(const unsigned short* __restrict__ g, int pitch,
                                       int r0, int k0, unsigned short* lds, int tid)
{
    #pragma unroll
    for (int i = 0; i < 4; ++i) {
        int u = i * 256 + tid;
        int row = u >> 3;
        int j = (u & 7) ^ (row & 7);
        const unsigned short* src = g + (long)(r0 + row) * pitch + k0 + j * 8;
        gload16(src, lds + u * 8);
    }
}

template<bool WF32, bool SPLIT, bool ADD, bool BIAS>
__global__ __launch_bounds__(256, 2) void gemm_split(
    const unsigned short* __restrict__ Ah, const unsigned short* __restrict__ Al,
    const unsigned short* __restrict__ Bh, const unsigned short* __restrict__ Bl,
    int K, long strideB,
    float* __restrict__ C, int ldc, int strideC,
    unsigned short* __restrict__ Ch, unsigned short* __restrict__ Cl, int ldch,
    const unsigned short* __restrict__ addh, const unsigned short* __restrict__ addl, int ldadd,
    const float* __restrict__ bias)
{
    __shared__ unsigned short sAh[128 * 64];
    __shared__ unsigned short sAl[128 * 64];
    __shared__ unsigned short sBh[128 * 64];
    __shared__ unsigned short sBl[128 * 64];

    const int tid  = threadIdx.x;
    const int row0 = blockIdx.y * 128;
    const int col0 = blockIdx.x * 128;
    const unsigned short* Bh_ = Bh + (long)blockIdx.z * strideB;
    const unsigned short* Bl_ = Bl + (long)blockIdx.z * strideB;
    const int cOff = blockIdx.z * strideC;

    const int lane = tid & 63;
    const int wv = tid >> 6;
    const int wr = (wv >> 1) * 64;
    const int wc = (wv & 1) * 64;
    const int fr = lane & 15;
    const int fc = lane >> 4;

    f32x4 acc[4][4];
    f32x4 z4 = {0.f, 0.f, 0.f, 0.f};
    #pragma unroll
    for (int m = 0; m < 4; ++m)
        #pragma unroll
        for (int n = 0; n < 4; ++n) acc[m][n] = z4;

    stage4(Ah, K, row0, 0, sAh, tid);
    stage4(Al, K, row0, 0, sAl, tid);
    stage4(Bh_, K, col0, 0, sBh, tid);
    stage4(Bl_, K, col0, 0, sBl, tid);

    const int nt = K >> 6;
    for (int kt = 0; kt < nt; ++kt) {
        __syncthreads();   // staging visible (compiler drains vmcnt before barrier)
        #pragma unroll
        for (int kk = 0; kk < 2; ++kk) {
            s16x8 va_h[4], va_l[4], vb_h[4], vb_l[4];
            #pragma unroll
            for (int m = 0; m < 4; ++m) {
                int rr = wr + m * 16 + fr;
                int off = rr * 64 + ((((kk << 2) + fc) ^ (rr & 7)) << 3);
                va_h[m] = *(const s16x8*)&sAh[off];
                va_l[m] = *(const s16x8*)&sAl[off];
            }
            #pragma unroll
            for (int n = 0; n < 4; ++n) {
                int rr = wc + n * 16 + fr;
                int off = rr * 64 + ((((kk << 2) + fc) ^ (rr & 7)) << 3);
                vb_h[n] = *(const s16x8*)&sBh[off];
                vb_l[n] = *(const s16x8*)&sBl[off];
            }
            #pragma unroll
            for (int m = 0; m < 4; ++m)
                #pragma unroll
                for (int n = 0; n < 4; ++n) {
                    acc[m][n] = __builtin_amdgcn_mfma_f32_16x16x32_bf16(va_h[m], vb_h[n], acc[m][n], 0, 0, 0);
                    acc[m][n] = __builtin_amdgcn_mfma_f32_16x16x32_bf16(va_l[m], vb_h[n], acc[m][n], 0, 0, 0);
                    acc[m][n] = __builtin_amdgcn_mfma_f32_16x16x32_bf16(va_h[m], vb_l[n], acc[m][n], 0, 0, 0);
                }
        }
        __syncthreads();   // all reads done before overwrite
        if (kt + 1 < nt) {
            int k0 = (kt + 1) << 6;
            stage4(Ah, K, row0, k0, sAh, tid);
            stage4(Al, K, row0, k0, sAl, tid);
            stage4(Bh_, K, col0, k0, sBh, tid);
            stage4(Bl_, K, col0, k0, sBl, tid);
        }
    }

    // epilogue: C/D layout col = lane&15, row = (lane>>4)*4 + r  [m89-verified]
    #pragma unroll
    for (int m = 0; m < 4; ++m) {
        #pragma unroll
        for (int n = 0; n < 4; ++n) {
            #pragma unroll
            for (int r = 0; r < 4; ++r) {
                int gr = row0 + wr + m * 16 + fc * 4 + r;
                int gc = col0 + wc + n * 16 + fr;
                float v = acc[m][n][r];
                if constexpr (BIAS) v += bias[gc];
                if constexpr (ADD) {
                    long ai = (long)gr * ldadd + gc;
                    v += bf2f(addh[ai]) + bf2f(addl[ai]);
                }
                if constexpr (WF32) C[(long)gr * ldc + cOff + gc] = v;
                if constexpr (SPLIT) {
                    long ci = (long)gr * ldch + gc;
                    unsigned short hb = f2bf(v);
                    Ch[ci] = hb;
                    Cl[ci] = f2bf(v - bf2f(hb));
                }
            }
        }
    }
}

// ---------------------------------------------------------------------------
// BN batch stats
__global__ void stats_partial(const float* __restrict__ h, float* __restrict__ sum,
                              float* __restrict__ sq, int C, int rows)
{
    int c  = blockIdx.x * 256 + threadIdx.x;
    int r0 = blockIdx.y * rows;
    const float* p = h + (long)r0 * C + c;
    float s = 0.f, ss = 0.f;
    for (int r = 0; r < rows; ++r) {
        float v = *p; p += C;
        s += v; ss += v * v;
    }
    atomicAdd(&sum[c], s);
    atomicAdd(&sq[c], ss);
}

__global__ void stats_final(const float* __restrict__ sum, const float* __restrict__ sq,
                            const float* __restrict__ g, const float* __restrict__ beta,
                            float* __restrict__ Asc, float* __restrict__ C0, int C)
{
    int c = blockIdx.x * 256 + threadIdx.x;
    if (c >= C) return;
    float mean = sum[c] * (1.f / (float)BB);
    float var  = sq[c] * (1.f / (float)BB) - mean * mean;
    var = fmaxf(var, 0.f);
    float a = g[c] / sqrtf(var + EPS);
    Asc[c] = a;
    C0[c]  = beta[c] - a * mean;
}

// ---------------------------------------------------------------------------
// combine: dst[b,o] = sum_e gate[b,e] * leaky(A[e,o]*h[b,e,o] + C0[e,o])
__global__ void combine_kernel(const float* __restrict__ h, const float* __restrict__ gate,
                               const float* __restrict__ Asc, const float* __restrict__ C0,
                               float* __restrict__ dstF,
                               unsigned short* __restrict__ dsth, unsigned short* __restrict__ dstl)
{
    int idx = blockIdx.x * 256 + threadIdx.x;
    int b = idx >> 10, o = idx & 1023;
    const float* hr = h + (long)b * (NE * DE) + o;
    const float* gr = gate + (long)b * NE;
    float s = 0.f;
    #pragma unroll
    for (int e = 0; e < NE; ++e) {
        int c = e * DE + o;
        float v = Asc[c] * hr[e * DE] + C0[c];
        v = v > 0.f ? v : 0.01f * v;
        s += gr[e] * v;
    }
    long oi = (long)b * DE + o;
    if (dstF) dstF[oi] = s;
    if (dsth) {
        unsigned short hb = f2bf(s);
        dsth[oi] = hb;
        dstl[oi] = f2bf(s - bf2f(hb));
    }
}

// ---------------------------------------------------------------------------
// SE block; emits split-bf16 latent
__global__ __launch_bounds__(256) void se_kernel(
    const float* __restrict__ mu, const float* __restrict__ Wse1,
    const float* __restrict__ Wse2,
    unsigned short* __restrict__ lath, unsigned short* __restrict__ latl)
{
    const int tid = threadIdx.x;
    const int lane = tid & 63, wid = tid >> 6;
    const int b = blockIdx.x * 4 + wid;
    const float* murow = mu + (long)b * DE;
    const int j = lane & 15, ch = lane >> 4;
    float acc = 0.f;
    const int obase = ch * 256;
    for (int t = 0; t < 256; ++t) {
        int o = obase + t;
        acc += murow[o] * Wse1[o * 16 + j];
    }
    acc += __shfl_down(acc, 16);
    acc += __shfl_down(acc, 32);
    float t2 = fmaxf(acc, 0.f);
    float t2v[16];
    #pragma unroll
    for (int jj = 0; jj < 16; ++jj) t2v[jj] = __shfl(t2, jj);
    for (int rep = 0; rep < 16; ++rep) {
        int o = rep * 64 + lane;
        float s = 0.f;
        #pragma unroll
        for (int jj = 0; jj < 16; ++jj) s += t2v[jj] * Wse2[jj * DE + o];
        float se = 1.f / (1.f + expf(-s));
        float lv = murow[o] * se;
        long oi = (long)b * DE + o;
        unsigned short hb = f2bf(lv);
        lath[oi] = hb;
        latl[oi] = f2bf(lv - bf2f(hb));
    }
}

// ---------------------------------------------------------------------------
__global__ void bn_norm(float* __restrict__ y, const float* __restrict__ Asc,
                        const float* __restrict__ C0, long n, int ld)
{
    long stride = (long)gridDim.x * 256;
    for (long i = blockIdx.x * 256L + threadIdx.x; i < n; i += stride) {
        int c = (int)(i & (ld - 1));
        float v = Asc[c] * y[i] + C0[c];
        y[i] = v > 0.f ? v : 0.01f * v;
    }
}

// ---------------------------------------------------------------------------
extern "C" void kernel_launch(void* const* d_in, const int* in_sizes, int n_in,
                              void* d_out, int out_size, void* d_ws, size_t ws_size,
                              hipStream_t stream)
{
    (void)in_sizes; (void)n_in; (void)out_size; (void)ws_size;
    const float* x     = (const float*)d_in[0];
    const float* We_mu = (const float*)d_in[1];
    // d_in[2] be_mu: dead (BN shift-invariance)
    const float* g_mu  = (const float*)d_in[3];
    const float* b_mu  = (const float*)d_in[4];
    const float* We_d  = (const float*)d_in[5];
    // d_in[6] be_d: dead
    const float* g_d   = (const float*)d_in[7];
    const float* b_d   = (const float*)d_in[8];
    const float* Wg1   = (const float*)d_in[9];
    const float* bg1   = (const float*)d_in[10];
    const float* Wg2   = (const float*)d_in[11];
    const float* bg2   = (const float*)d_in[12];
    // d_in[13] Wq, d_in[14] Wk: dead (softmax over size-1 axis == 1)
    const float* Wv    = (const float*)d_in[15];
    const float* Wp    = (const float*)d_in[16];
    const float* bp    = (const float*)d_in[17];
    const float* Wse1  = (const float*)d_in[18];
    const float* Wse2  = (const float*)d_in[19];
    const float* Wd    = (const float*)d_in[20];
    // d_in[21] bd: dead
    const float* g_dec = (const float*)d_in[22];
    const float* b_dec = (const float*)d_in[23];

    // ---- workspace layout (~225 MB peak) ----
    char* base = (char*)d_ws;
    float*          h    = (float*)(base);                       // 96 MiB  [B][E*DE]
    unsigned short* xh   = (unsigned short*)(base + 100663296);  // 32 MiB
    unsigned short* xl   = (unsigned short*)(base + 134217728);  // 32 MiB
    unsigned short* Wth  = (unsigned short*)(base + 167772160);  // 24 MiB (3 experts)
    unsigned short* Wtl  = (unsigned short*)(base + 192937984);  // 24 MiB
    unsigned short* mu0h = (unsigned short*)(base + 218103808);  //  8 MiB
    unsigned short* mu0l = (unsigned short*)(base + 226492416);  //  8 MiB
    float*          gate = (float*)(base + 234881024);
    float*          t1   = (float*)(base + 234979328);
    float*          ssum = (float*)(base + 236027904);
    float*          ssq  = (float*)(base + 236052480);
    float*          Asc  = (float*)(base + 236077056);
    float*          C0v  = (float*)(base + 236101632);

    // aliases into h region — valid only after the expert phase is done
    char* hb = (char*)h;
    unsigned short* vh   = (unsigned short*)(hb);
    unsigned short* vl   = (unsigned short*)(hb + 8388608);
    unsigned short* lath = (unsigned short*)(hb + 16777216);
    unsigned short* latl = (unsigned short*)(hb + 25165824);
    unsigned short* WvTh = (unsigned short*)(hb + 33554432);
    unsigned short* WvTl = (unsigned short*)(hb + 35651584);
    unsigned short* WpTh = (unsigned short*)(hb + 37748736);
    unsigned short* WpTl = (unsigned short*)(hb + 39845888);
    unsigned short* WdTh = (unsigned short*)(hb + 41943040);
    unsigned short* WdTl = (unsigned short*)(hb + 50331648);

    float* out    = (float*)d_out;              // [B, DIN]
    float* mu_out = out + (long)BB * DIN;       // [B, DE]
    float* d_outv = mu_out + (long)BB * DE;     // [B, DE]

    dim3 blk(256);
    const long sExp = (long)DIN * DE;           // elements per expert weight

    // input split + gating
    split_k<<<2048, blk, 0, stream>>>(x, xh, xl, (long)BB * DIN / 4);
    zero_k<<<1024, blk, 0, stream>>>(t1, 262144);
    gate1_kernel<<<dim3(64, 4), blk, 0, stream>>>(x, Wg1, t1);
    gate2_kernel<<<16, blk, 0, stream>>>(t1, Wg2, bg1, bg2, gate);

    // ---- expert branches: 2 groups of 3 experts each (Wt buffers are 3-wide) ----
    for (int branch = 0; branch < 2; ++branch) {
        const float* We = branch ? We_d : We_mu;
        for (int grp = 0; grp < 2; ++grp) {
            tsplit_k<<<dim3(32, 128, 3), blk, 0, stream>>>(
                We + (long)grp * 3 * sExp, Wth, Wtl, DIN, DE, sExp, sExp);
            gemm_split<true, false, false, false><<<dim3(8, 32, 3), blk, 0, stream>>>(
                xh, xl, Wth, Wtl, DIN, sExp,
                h + (long)grp * 3 * DE, NE * DE, DE,
                nullptr, nullptr, 0, nullptr, nullptr, 0, nullptr);
        }
        zero_k<<<48, blk, 0, stream>>>(ssum, 12288);
        stats_partial<<<dim3(24, 32), blk, 0, stream>>>(h, ssum, ssq, NE * DE, 128);
        if (branch == 0) {
            stats_final<<<24, blk, 0, stream>>>(ssum, ssq, g_mu, b_mu, Asc, C0v, NE * DE);
            combine_kernel<<<16384, blk, 0, stream>>>(h, gate, Asc, C0v, nullptr, mu0h, mu0l);
        } else {
            stats_final<<<24, blk, 0, stream>>>(ssum, ssq, g_d, b_d, Asc, C0v, NE * DE);
            combine_kernel<<<16384, blk, 0, stream>>>(h, gate, Asc, C0v, d_outv, nullptr, nullptr);
        }
    }

    // ---- attention (attn==1): mu = mu0 + (mu0@Wv)@Wp + bp ----
    tsplit_k<<<dim3(32, 32, 1), blk, 0, stream>>>(Wv, WvTh, WvTl, DE, DE, 0, 0);
    tsplit_k<<<dim3(32, 32, 1), blk, 0, stream>>>(Wp, WpTh, WpTl, DE, DE, 0, 0);
    tsplit_k<<<dim3(128, 32, 1), blk, 0, stream>>>(Wd, WdTh, WdTl, DE, DIN, 0, 0);
    gemm_split<false, true, false, false><<<dim3(8, 32, 1), blk, 0, stream>>>(
        mu0h, mu0l, WvTh, WvTl, DE, 0,
        nullptr, 0, 0, vh, vl, DE, nullptr, nullptr, 0, nullptr);
    gemm_split<true, false, true, true><<<dim3(8, 32, 1), blk, 0, stream>>>(
        vh, vl, WpTh, WpTl, DE, 0,
        mu_out, DE, 0, nullptr, nullptr, 0, mu0h, mu0l, DE, bp);

    // ---- SE gate -> split latent ----
    se_kernel<<<1024, blk, 0, stream>>>(mu_out, Wse1, Wse2, lath, latl);

    // ---- decoder ----
    gemm_split<true, false, false, false><<<dim3(32, 32, 1), blk, 0, stream>>>(
        lath, latl, WdTh, WdTl, DE, 0,
        out, DIN, 0, nullptr, nullptr, 0, nullptr, nullptr, 0, nullptr);
    zero_k<<<48, blk, 0, stream>>>(ssum, 12288);
    stats_partial<<<dim3(16, 32), blk, 0, stream>>>(out, ssum, ssq, DIN, 128);
    stats_final<<<16, blk, 0, stream>>>(ssum, ssq, g_dec, b_dec, Asc, C0v, DIN);
    bn_norm<<<4096, blk, 0, stream>>>(out, Asc, C0v, (long)BB * DIN, DIN);
}